// Round 4
// baseline (769.472 us; speedup 1.0000x reference)
//
#include <hip/hip_runtime.h>
#include <stdint.h>

typedef unsigned short u16;
typedef __attribute__((ext_vector_type(8))) short s16x8;
typedef __attribute__((ext_vector_type(4))) float f32x4;

#define B_   2
#define T_   2048
#define DM   2048
#define H_   16
#define HD_  128
#define R_   64
#define E_   192
#define SCALE 0.07216878364870323f  // 1/sqrt(192)

__device__ __forceinline__ u16 f2b(float f) {
  union { float f; uint32_t u; } x; x.f = f;
  uint32_t u = x.u;
  return (u16)((u + 0x7FFFu + ((u >> 16) & 1u)) >> 16);  // RNE
}
__device__ __forceinline__ float b2f(u16 h) {
  union { uint32_t u; float f; } x; x.u = ((uint32_t)h) << 16;
  return x.f;
}

// ---------- input convert fp32 -> bf16 ----------
__global__ __launch_bounds__(256) void conv_k(const float* __restrict__ in, u16* __restrict__ out, int n) {
  int i = blockIdx.x * 256 + threadIdx.x;
  if (i * 4 >= n) return;
  float4 v = *(const float4*)(in + i * 4);
  ushort4 o;
  o.x = f2b(v.x); o.y = f2b(v.y); o.z = f2b(v.z); o.w = f2b(v.w);
  *(ushort4*)(out + i * 4) = o;
}

// ---------- weight transpose (K,N) fp32 -> (N,K) bf16 ----------
__global__ __launch_bounds__(256) void transpose_k(const float* __restrict__ in, u16* __restrict__ out,
                                                   int K, int N) {
  __shared__ u16 t[64][65];
  int bn = blockIdx.x * 64, bk = blockIdx.y * 64;
  int tid = threadIdx.x;
  int r0 = tid >> 4, c0 = (tid & 15) * 4;
#pragma unroll
  for (int rr = 0; rr < 64; rr += 16) {
    float4 v = *(const float4*)(in + (size_t)(bk + r0 + rr) * N + bn + c0);
    t[r0 + rr][c0 + 0] = f2b(v.x); t[r0 + rr][c0 + 1] = f2b(v.y);
    t[r0 + rr][c0 + 2] = f2b(v.z); t[r0 + rr][c0 + 3] = f2b(v.w);
  }
  __syncthreads();
#pragma unroll
  for (int rr = 0; rr < 64; rr += 16) {
    ushort4 v;
    v.x = t[c0 + 0][r0 + rr]; v.y = t[c0 + 1][r0 + rr];
    v.z = t[c0 + 2][r0 + rr]; v.w = t[c0 + 3][r0 + rr];
    *(ushort4*)(out + (size_t)(bn + r0 + rr) * K + bk + c0) = v;
  }
}

// ---------------- GEMM: C(M,N) = A(M,K) * Bt(N,K)^T, bf16 in, fp32 acc ----------------
// EPI 0: bf16 C0.  EPI 1: V^T bf16 C0.  EPI 2: fp32 C1.  EPI 3: bf16 C0 + fp32 C1.
template <int EPI>
__global__ __launch_bounds__(256)
void gemm_bf16(const u16* __restrict__ A, const u16* __restrict__ Bt,
               u16* __restrict__ C0, float* __restrict__ C1,
               int M, int N, int K) {
  __shared__ __align__(16) u16 Al[128 * 32];
  __shared__ __align__(16) u16 Bl[128 * 32];
  const int tid = threadIdx.x;
  const int ln = tid & 63, w = tid >> 6;
  const int quad = ln >> 4, l16 = ln & 15;
  const int wm = (w >> 1) * 64, wn = (w & 1) * 64;
  const int m0 = blockIdx.y * 128, n0 = blockIdx.x * 128;

  f32x4 zz = {0.f, 0.f, 0.f, 0.f};
  f32x4 acc[4][4];
#pragma unroll
  for (int i = 0; i < 4; i++)
#pragma unroll
    for (int j = 0; j < 4; j++) acc[i][j] = zz;

  const u16* aG[2];
  const u16* bG[2];
#pragma unroll
  for (int r = 0; r < 2; r++) {
    int i = tid + r * 256;
    int row = i >> 2, cq = (i & 3) * 8;
    aG[r] = A + (size_t)(m0 + row) * K + cq;
    int rb = n0 + row;
    if (rb > N - 1) rb = N - 1;  // clamp for N<128 tiles (dup rows, cols discarded)
    bG[r] = Bt + (size_t)rb * K + cq;
  }

  for (int k = 0; k < K; k += 32) {
    s16x8 av[2], bv[2];
#pragma unroll
    for (int r = 0; r < 2; r++) {
      av[r] = *(const s16x8*)(aG[r] + k);
      bv[r] = *(const s16x8*)(bG[r] + k);
    }
    __syncthreads();
#pragma unroll
    for (int r = 0; r < 2; r++) {
      *(s16x8*)&Al[(tid + r * 256) * 8] = av[r];
      *(s16x8*)&Bl[(tid + r * 256) * 8] = bv[r];
    }
    __syncthreads();
    s16x8 af[4], bf[4];
#pragma unroll
    for (int f = 0; f < 4; f++)
      af[f] = *(const s16x8*)&Al[(wm + f * 16 + l16) * 32 + quad * 8];
#pragma unroll
    for (int f = 0; f < 4; f++)
      bf[f] = *(const s16x8*)&Bl[(wn + f * 16 + l16) * 32 + quad * 8];
#pragma unroll
    for (int i = 0; i < 4; i++)
#pragma unroll
      for (int j = 0; j < 4; j++)
        acc[i][j] = __builtin_amdgcn_mfma_f32_16x16x32_bf16(af[i], bf[j], acc[i][j], 0, 0, 0);
  }

#pragma unroll
  for (int fm = 0; fm < 4; fm++) {
#pragma unroll
    for (int fn = 0; fn < 4; fn++) {
      int n = n0 + wn + fn * 16 + l16;
      int mb = m0 + wm + fm * 16 + quad * 4;
      if (EPI == 1) {
        // V^T: m=(b,t) n=(h,hd); out idx = (b*2048 + n)*2048 + t
        int b = mb >> 11, t = mb & 2047;
        ushort4 v;
        v.x = f2b(acc[fm][fn][0]); v.y = f2b(acc[fm][fn][1]);
        v.z = f2b(acc[fm][fn][2]); v.w = f2b(acc[fm][fn][3]);
        *(ushort4*)(C0 + ((size_t)(b * 2048 + n) * 2048 + t)) = v;
      } else if (n < N) {
#pragma unroll
        for (int rg = 0; rg < 4; rg++) {
          float v = acc[fm][fn][rg];
          size_t idx = (size_t)(mb + rg) * N + n;
          if (EPI == 0 || EPI == 3) C0[idx] = f2b(v);
          if (EPI == 2 || EPI == 3) C1[idx] = v;
        }
      }
    }
  }
}

// ---------------- RoPE ----------------
__global__ __launch_bounds__(256) void rope_k(const u16* __restrict__ in, const u16* __restrict__ fr,
                                              u16* __restrict__ out_ws, float* __restrict__ out_io) {
  int i = blockIdx.x * 256 + threadIdx.x;  // pair index over (b,t,32)
  int r2 = i & 31, t = (i >> 5) & (T_ - 1);
  float x0 = b2f(in[2 * i]), x1 = b2f(in[2 * i + 1]);
  float a = b2f(fr[t * 32 + r2]);
  float sn, cs;
  __sincosf(a, &sn, &cs);
  float y0 = x0 * cs - x1 * sn, y1 = x0 * sn + x1 * cs;
  out_ws[2 * i] = f2b(y0); out_ws[2 * i + 1] = f2b(y1);
  out_io[2 * i] = y0; out_io[2 * i + 1] = y1;
}
__global__ __launch_bounds__(256) void rope_q(u16* __restrict__ x, const u16* __restrict__ fr) {
  int i = blockIdx.x * 256 + threadIdx.x;  // pair index over (b,t,h,32)
  int r2 = i & 31, t = (i >> 9) & (T_ - 1);
  float x0 = b2f(x[2 * i]), x1 = b2f(x[2 * i + 1]);
  float a = b2f(fr[t * 32 + r2]);
  float sn, cs;
  __sincosf(a, &sn, &cs);
  x[2 * i] = f2b(x0 * cs - x1 * sn);
  x[2 * i + 1] = f2b(x0 * sn + x1 * cs);
}

// ---------------- flash attention: block = (b,h, 64 q rows), 4 waves x 16 rows ----------------
__global__ __launch_bounds__(256)
void flash_attn(const u16* __restrict__ Qc, const u16* __restrict__ Qr,
                const u16* __restrict__ Kc, const u16* __restrict__ Kr,
                const u16* __restrict__ VT, u16* __restrict__ O) {
  __shared__ __align__(16) u16 Kt[32 * E_];
  __shared__ __align__(16) u16 Vt[HD_ * 32];
  __shared__ __align__(16) u16 Ps[4][16 * 32];

  const int tid = threadIdx.x;
  const int ln = tid & 63, w = tid >> 6;
  const int quad = ln >> 4, l16 = ln & 15;
  const int bh = blockIdx.y, b = bh >> 4, h = bh & 15;
  const int q0 = blockIdx.x * 64;
  const int qw = q0 + w * 16;

  s16x8 qf[6];
  {
    int t = qw + l16;
    const u16* p = Qc + ((size_t)(b * T_ + t) * DM + h * HD_ + quad * 8);
#pragma unroll
    for (int f = 0; f < 4; f++) qf[f] = *(const s16x8*)(p + f * 32);
    const u16* pr = Qr + ((size_t)(b * T_ + t) * (H_ * R_) + h * R_ + quad * 8);
#pragma unroll
    for (int f = 0; f < 2; f++) qf[4 + f] = *(const s16x8*)(pr + f * 32);
  }

  f32x4 zz = {0.f, 0.f, 0.f, 0.f};
  f32x4 o[8];
#pragma unroll
  for (int f = 0; f < 8; f++) o[f] = zz;
  float mrow[4], lrow[4];
#pragma unroll
  for (int rg = 0; rg < 4; rg++) { mrow[rg] = -1e30f; lrow[rg] = 0.f; }

  const int nk = q0 + 64;
  for (int k0 = 0; k0 < nk; k0 += 32) {
    s16x8 kv[3], vv[2];
#pragma unroll
    for (int r = 0; r < 3; r++) {
      int i = tid + r * 256;
      int key = i / 24, c = i - key * 24;
      const u16* g;
      if (c < 16) g = Kc + ((size_t)(b * T_ + k0 + key) * DM + h * HD_ + c * 8);
      else        g = Kr + ((size_t)(b * T_ + k0 + key) * R_ + (c - 16) * 8);
      kv[r] = *(const s16x8*)g;
    }
#pragma unroll
    for (int r = 0; r < 2; r++) {
      int i = tid + r * 256;
      vv[r] = *(const s16x8*)(VT + ((size_t)(bh * HD_ + (i >> 2)) * T_ + k0 + (i & 3) * 8));
    }
    __syncthreads();
#pragma unroll
    for (int r = 0; r < 3; r++) *(s16x8*)&Kt[(tid + r * 256) * 8] = kv[r];
#pragma unroll
    for (int r = 0; r < 2; r++) *(s16x8*)&Vt[(tid + r * 256) * 8] = vv[r];
    __syncthreads();

    const bool active = (k0 <= qw + 15);  // wave-uniform
    if (active) {
      f32x4 s[2];
      s[0] = zz; s[1] = zz;
#pragma unroll
      for (int fk = 0; fk < 2; fk++)
#pragma unroll
        for (int e = 0; e < 6; e++) {
          s16x8 kf = *(const s16x8*)&Kt[(fk * 16 + l16) * E_ + e * 32 + quad * 8];
          s[fk] = __builtin_amdgcn_mfma_f32_16x16x32_bf16(qf[e], kf, s[fk], 0, 0, 0);
        }
#pragma unroll
      for (int rg = 0; rg < 4; rg++) {
        int q = qw + quad * 4 + rg;
        float s0 = s[0][rg] * SCALE; if (k0 + l16 > q) s0 = -1e30f;
        float s1 = s[1][rg] * SCALE; if (k0 + 16 + l16 > q) s1 = -1e30f;
        float mx = fmaxf(s0, s1);
        mx = fmaxf(mx, __shfl_xor(mx, 1));
        mx = fmaxf(mx, __shfl_xor(mx, 2));
        mx = fmaxf(mx, __shfl_xor(mx, 4));
        mx = fmaxf(mx, __shfl_xor(mx, 8));
        float mn = fmaxf(mrow[rg], mx);
        float e0 = __expf(s0 - mn);
        float e1 = __expf(s1 - mn);
        float rs = e0 + e1;
        rs += __shfl_xor(rs, 1);
        rs += __shfl_xor(rs, 2);
        rs += __shfl_xor(rs, 4);
        rs += __shfl_xor(rs, 8);
        float alpha = __expf(mrow[rg] - mn);
        lrow[rg] = lrow[rg] * alpha + rs;
        mrow[rg] = mn;
#pragma unroll
        for (int f = 0; f < 8; f++) o[f][rg] *= alpha;
        Ps[w][(quad * 4 + rg) * 32 + l16] = f2b(e0);
        Ps[w][(quad * 4 + rg) * 32 + 16 + l16] = f2b(e1);
      }
    }
    __syncthreads();
    if (active) {
      s16x8 pa = *(const s16x8*)&Ps[w][l16 * 32 + quad * 8];
#pragma unroll
      for (int f = 0; f < 8; f++) {
        s16x8 vb = *(const s16x8*)&Vt[(f * 16 + l16) * 32 + quad * 8];
        o[f] = __builtin_amdgcn_mfma_f32_16x16x32_bf16(pa, vb, o[f], 0, 0, 0);
      }
    }
  }

#pragma unroll
  for (int f = 0; f < 8; f++) {
#pragma unroll
    for (int rg = 0; rg < 4; rg++) {
      int q = qw + quad * 4 + rg;
      float v = o[f][rg] / lrow[rg];
      O[(size_t)(b * T_ + q) * DM + h * HD_ + f * 16 + l16] = f2b(v);
    }
  }
}

// ---------------- launch ----------------
extern "C" void kernel_launch(void* const* d_in, const int* in_sizes, int n_in,
                              void* d_out, int out_size, void* d_ws, size_t ws_size,
                              hipStream_t stream) {
  const float* x    = (const float*)d_in[0];
  const float* fr   = (const float*)d_in[1];
  const float* wdkv = (const float*)d_in[2];
  const float* wuk  = (const float*)d_in[3];
  const float* wuv  = (const float*)d_in[4];
  const float* wkr  = (const float*)d_in[5];
  const float* wdq  = (const float*)d_in[6];
  const float* wuq  = (const float*)d_in[7];
  const float* wqr  = (const float*)d_in[8];
  const float* wo   = (const float*)d_in[9];
  u16* ws = (u16*)d_ws;

  const int M1 = 1048576;
  u16* x_bf  = ws;                 // 8M  (dead after c_Q gemm) -> Om overlays
  u16* Om    = ws;                 // 8M  [flash..final gemm]
  u16* Kc    = ws + 8 * M1;        // 8M  (b,t,h*hd)
  u16* VTm   = ws + 16 * M1;       // 8M  (b,h*hd,t)
  u16* Qc    = ws + 24 * M1;       // 8M  (b,t,h*hd)
  u16* Qr    = ws + 32 * M1;       // 4M  (b,t,h,r)
  u16* W     = ws + 36 * M1;       // 4M  weight-transpose slot (serial reuse)
  u16* cKV   = ws + 40 * M1;       // 2M
  u16* cQ    = ws + 42 * M1;       // 4M
  u16* xKR   = ws + 46 * M1;       // 262144
  u16* fr_bf = xKR + 262144;       // 65536
  u16* kr_bf = fr_bf + 65536;      // 262144

  // fp32 outputs, float-element offsets
  float* out_y   = (float*)d_out;              // (b,t,2048)
  float* out_ckv = (float*)d_out + 8388608;    // (b,t,512)
  float* out_kr  = (float*)d_out + 10485760;   // (b,t,64)
  (void)in_sizes; (void)n_in; (void)out_size; (void)ws_size;

  dim3 blk(256);

  conv_k<<<dim3(8192), blk, 0, stream>>>(x, x_bf, 8388608);
  conv_k<<<dim3(64), blk, 0, stream>>>(fr, fr_bf, 65536);

  // c_KV = x @ W_DKV  (bf16 ws + fp32 out)
  transpose_k<<<dim3(8, 32), blk, 0, stream>>>(wdkv, W, 2048, 512);
  gemm_bf16<3><<<dim3(4, 32), blk, 0, stream>>>(x_bf, W, cKV, out_ckv, 4096, 512, 2048);
  // K_c = c_KV @ W_UK
  transpose_k<<<dim3(32, 8), blk, 0, stream>>>(wuk, W, 512, 2048);
  gemm_bf16<0><<<dim3(16, 32), blk, 0, stream>>>(cKV, W, Kc, nullptr, 4096, 2048, 512);
  // V^T = (c_KV @ W_UV)^T  (stored (b,h,hd,t))
  transpose_k<<<dim3(32, 8), blk, 0, stream>>>(wuv, W, 512, 2048);
  gemm_bf16<1><<<dim3(16, 32), blk, 0, stream>>>(cKV, W, VTm, nullptr, 4096, 2048, 512);
  // K_r = rope(x @ W_KR)  (bf16 ws + fp32 out)
  transpose_k<<<dim3(1, 32), blk, 0, stream>>>(wkr, W, 2048, 64);
  gemm_bf16<0><<<dim3(1, 32), blk, 0, stream>>>(x_bf, W, xKR, nullptr, 4096, 64, 2048);
  rope_k<<<dim3(512), blk, 0, stream>>>(xKR, fr_bf, kr_bf, out_kr);
  // c_Q = x @ W_DQ
  transpose_k<<<dim3(16, 32), blk, 0, stream>>>(wdq, W, 2048, 1024);
  gemm_bf16<0><<<dim3(8, 32), blk, 0, stream>>>(x_bf, W, cQ, nullptr, 4096, 1024, 2048);
  // Q_c = c_Q @ W_UQ
  transpose_k<<<dim3(32, 16), blk, 0, stream>>>(wuq, W, 1024, 2048);
  gemm_bf16<0><<<dim3(16, 32), blk, 0, stream>>>(cQ, W, Qc, nullptr, 4096, 2048, 1024);
  // Q_r = rope(c_Q @ W_QR)
  transpose_k<<<dim3(16, 16), blk, 0, stream>>>(wqr, W, 1024, 1024);
  gemm_bf16<0><<<dim3(8, 32), blk, 0, stream>>>(cQ, W, Qr, nullptr, 4096, 1024, 1024);
  rope_q<<<dim3(8192), blk, 0, stream>>>(Qr, fr_bf);
  // attention (Om overlays dead x_bf region)
  flash_attn<<<dim3(32, 32), blk, 0, stream>>>(Qc, Qr, Kc, kr_bf, VTm, Om);
  // y = attn_out @ W_O  (fp32 out)
  transpose_k<<<dim3(32, 32), blk, 0, stream>>>(wo, W, 2048, 2048);
  gemm_bf16<2><<<dim3(16, 32), blk, 0, stream>>>(Om, W, nullptr, out_y, 4096, 2048, 2048);
}

// Round 5
// 608.966 us; speedup vs baseline: 1.2636x; 1.2636x over previous
//
#include <hip/hip_runtime.h>
#include <stdint.h>

typedef unsigned short u16;
typedef __attribute__((ext_vector_type(8))) short s16x8;
typedef __attribute__((ext_vector_type(4))) float f32x4;

#define B_   2
#define T_   2048
#define DM   2048
#define H_   16
#define HD_  128
#define R_   64
#define E_   192
// 1/sqrt(192) * log2(e): softmax in base-2 domain
#define SCALE2 0.104117542f

__device__ __forceinline__ u16 f2b(float f) {
  union { float f; uint32_t u; } x; x.f = f;
  uint32_t u = x.u;
  return (u16)((u + 0x7FFFu + ((u >> 16) & 1u)) >> 16);  // RNE
}
__device__ __forceinline__ float b2f(u16 h) {
  union { uint32_t u; float f; } x; x.u = ((uint32_t)h) << 16;
  return x.f;
}
// async global->LDS, 16B/lane; LDS dest = wave-uniform base + lane*16
__device__ __forceinline__ void ld_lds16(const void* g, void* l) {
  __builtin_amdgcn_global_load_lds((const __attribute__((address_space(1))) void*)g,
                                   (__attribute__((address_space(3))) void*)l,
                                   16, 0, 0);
}

// ---------- input convert fp32 -> bf16 ----------
__global__ __launch_bounds__(256) void conv_k(const float* __restrict__ in, u16* __restrict__ out, int n) {
  int i = blockIdx.x * 256 + threadIdx.x;
  if (i * 4 >= n) return;
  float4 v = *(const float4*)(in + i * 4);
  ushort4 o;
  o.x = f2b(v.x); o.y = f2b(v.y); o.z = f2b(v.z); o.w = f2b(v.w);
  *(ushort4*)(out + i * 4) = o;
}

// ---------- weight transpose (K,N) fp32 -> (N,K) bf16 ----------
__global__ __launch_bounds__(256) void transpose_k(const float* __restrict__ in, u16* __restrict__ out,
                                                   int K, int N) {
  __shared__ u16 t[64][65];
  int bn = blockIdx.x * 64, bk = blockIdx.y * 64;
  int tid = threadIdx.x;
  int r0 = tid >> 4, c0 = (tid & 15) * 4;
#pragma unroll
  for (int rr = 0; rr < 64; rr += 16) {
    float4 v = *(const float4*)(in + (size_t)(bk + r0 + rr) * N + bn + c0);
    t[r0 + rr][c0 + 0] = f2b(v.x); t[r0 + rr][c0 + 1] = f2b(v.y);
    t[r0 + rr][c0 + 2] = f2b(v.z); t[r0 + rr][c0 + 3] = f2b(v.w);
  }
  __syncthreads();
#pragma unroll
  for (int rr = 0; rr < 64; rr += 16) {
    ushort4 v;
    v.x = t[c0 + 0][r0 + rr]; v.y = t[c0 + 1][r0 + rr];
    v.z = t[c0 + 2][r0 + rr]; v.w = t[c0 + 3][r0 + rr];
    *(ushort4*)(out + (size_t)(bn + r0 + rr) * K + bk + c0) = v;
  }
}

// ---------------- GEMM: C(M,N) = A(M,K) * Bt(N,K)^T, bf16 in, fp32 acc ----------------
// m97 structure: global_load_lds width-16 staging, 2-barrier K-loop.
// EPI 0: bf16 C0.  EPI 1: V^T bf16 C0.  EPI 2: fp32 C1.  EPI 3: bf16 C0 + fp32 C1.
template <int EPI>
__global__ __launch_bounds__(256)
void gemm_bf16(const u16* __restrict__ A, const u16* __restrict__ Bt,
               u16* __restrict__ C0, float* __restrict__ C1,
               int M, int N, int K) {
  __shared__ __align__(16) u16 Al[128 * 32];
  __shared__ __align__(16) u16 Bl[128 * 32];
  const int tid = threadIdx.x;
  const int ln = tid & 63, w = tid >> 6;
  const int quad = ln >> 4, l16 = ln & 15;
  const int wm = (w >> 1) * 64, wn = (w & 1) * 64;
  const int m0 = blockIdx.y * 128, n0 = blockIdx.x * 128;

  f32x4 zz = {0.f, 0.f, 0.f, 0.f};
  f32x4 acc[4][4];
#pragma unroll
  for (int i = 0; i < 4; i++)
#pragma unroll
    for (int j = 0; j < 4; j++) acc[i][j] = zz;

  const u16* aG[2];
  const u16* bG[2];
  int ldsC[2];
#pragma unroll
  for (int r = 0; r < 2; r++) {
    int i = tid + r * 256;
    int row = i >> 2, cq = (i & 3) * 8;
    aG[r] = A + (size_t)(m0 + row) * K + cq;
    int rb = n0 + row;
    if (rb > N - 1) rb = N - 1;  // clamp for N<128 tiles (dup rows, cols discarded)
    bG[r] = Bt + (size_t)rb * K + cq;
    ldsC[r] = ((tid & ~63) + r * 256) * 8;  // wave-uniform chunk base (shorts)
  }

  for (int k = 0; k < K; k += 32) {
#pragma unroll
    for (int r = 0; r < 2; r++) {
      ld_lds16(aG[r] + k, &Al[ldsC[r]]);
      ld_lds16(bG[r] + k, &Bl[ldsC[r]]);
    }
    __syncthreads();  // drains vmcnt, staging visible
    s16x8 af[4], bf[4];
#pragma unroll
    for (int f = 0; f < 4; f++)
      af[f] = *(const s16x8*)&Al[(wm + f * 16 + l16) * 32 + quad * 8];
#pragma unroll
    for (int f = 0; f < 4; f++)
      bf[f] = *(const s16x8*)&Bl[(wn + f * 16 + l16) * 32 + quad * 8];
#pragma unroll
    for (int i = 0; i < 4; i++)
#pragma unroll
      for (int j = 0; j < 4; j++)
        acc[i][j] = __builtin_amdgcn_mfma_f32_16x16x32_bf16(af[i], bf[j], acc[i][j], 0, 0, 0);
    __syncthreads();  // all reads done before next overwrite
  }

#pragma unroll
  for (int fm = 0; fm < 4; fm++) {
#pragma unroll
    for (int fn = 0; fn < 4; fn++) {
      int n = n0 + wn + fn * 16 + l16;
      int mb = m0 + wm + fm * 16 + quad * 4;
      if (EPI == 1) {
        // V^T: m=(b,t) n=(h,hd); out idx = (b*2048 + n)*2048 + t
        int b = mb >> 11, t = mb & 2047;
        ushort4 v;
        v.x = f2b(acc[fm][fn][0]); v.y = f2b(acc[fm][fn][1]);
        v.z = f2b(acc[fm][fn][2]); v.w = f2b(acc[fm][fn][3]);
        *(ushort4*)(C0 + ((size_t)(b * 2048 + n) * 2048 + t)) = v;
      } else if (n < N) {
#pragma unroll
        for (int rg = 0; rg < 4; rg++) {
          float v = acc[fm][fn][rg];
          size_t idx = (size_t)(mb + rg) * N + n;
          if (EPI == 0 || EPI == 3) C0[idx] = f2b(v);
          if (EPI == 2 || EPI == 3) C1[idx] = v;
        }
      }
    }
  }
}

// ---------------- RoPE ----------------
__global__ __launch_bounds__(256) void rope_k(const u16* __restrict__ in, const u16* __restrict__ fr,
                                              u16* __restrict__ out_ws, float* __restrict__ out_io) {
  int i = blockIdx.x * 256 + threadIdx.x;  // pair index over (b,t,32)
  int r2 = i & 31, t = (i >> 5) & (T_ - 1);
  float x0 = b2f(in[2 * i]), x1 = b2f(in[2 * i + 1]);
  float a = b2f(fr[t * 32 + r2]);
  float sn, cs;
  __sincosf(a, &sn, &cs);
  float y0 = x0 * cs - x1 * sn, y1 = x0 * sn + x1 * cs;
  out_ws[2 * i] = f2b(y0); out_ws[2 * i + 1] = f2b(y1);
  out_io[2 * i] = y0; out_io[2 * i + 1] = y1;
}
__global__ __launch_bounds__(256) void rope_q(u16* __restrict__ x, const u16* __restrict__ fr) {
  int i = blockIdx.x * 256 + threadIdx.x;  // pair index over (b,t,h,32)
  int r2 = i & 31, t = (i >> 9) & (T_ - 1);
  float x0 = b2f(x[2 * i]), x1 = b2f(x[2 * i + 1]);
  float a = b2f(fr[t * 32 + r2]);
  float sn, cs;
  __sincosf(a, &sn, &cs);
  x[2 * i] = f2b(x0 * cs - x1 * sn);
  x[2 * i + 1] = f2b(x0 * sn + x1 * cs);
}

// ---------------- flash attention ----------------
// Block = (b,h) x paired q-tiles {x, 31-x} of 64 rows -> uniform 66 k-iters/block.
// 4 waves x 16 q-rows. Padded LDS (conflict-free). Register-prefetch pipeline.
#define KT_S 200  // Kt row stride (shorts): 100 dwords = 4 mod 32
#define VT_S 40   // Vt/Ps row stride: 20 dwords
__global__ __launch_bounds__(256)
void flash_attn(const u16* __restrict__ Qc, const u16* __restrict__ Qr,
                const u16* __restrict__ Kc, const u16* __restrict__ Kr,
                const u16* __restrict__ VT, u16* __restrict__ O) {
  __shared__ __align__(16) u16 Kt[32 * KT_S];     // [key][e]   12.8 KB
  __shared__ __align__(16) u16 Vt[HD_ * VT_S];    // [hd][key]  10.24 KB
  __shared__ __align__(16) u16 Ps[4][16 * VT_S];  // per-wave P  5.12 KB

  const int tid = threadIdx.x;
  const int ln = tid & 63, w = tid >> 6;
  const int quad = ln >> 4, l16 = ln & 15;
  const int bh = blockIdx.y, b = bh >> 4, h = bh & 15;

  // staging maps (tile-invariant)
  const u16* kBase[3]; int kStep[3], kLds[3];
#pragma unroll
  for (int r = 0; r < 3; r++) {
    int i = tid + r * 256;
    int key = i / 24, c = i - key * 24;
    kLds[r] = key * KT_S + c * 8;
    if (c < 16) { kBase[r] = Kc + ((size_t)(b * T_ + key) * DM + h * HD_ + c * 8); kStep[r] = 32 * DM; }
    else        { kBase[r] = Kr + ((size_t)(b * T_ + key) * R_ + (c - 16) * 8);    kStep[r] = 32 * R_; }
  }
  const u16* vBase[2]; int vLds[2];
#pragma unroll
  for (int r = 0; r < 2; r++) {
    int i = tid + r * 256;
    vLds[r] = (i >> 2) * VT_S + (i & 3) * 8;
    vBase[r] = VT + ((size_t)(bh * HD_ + (i >> 2)) * T_ + (i & 3) * 8);
  }

  f32x4 zz = {0.f, 0.f, 0.f, 0.f};
  const int xs0 = blockIdx.x, xs1 = 31 - (int)blockIdx.x;

  for (int tt = 0; tt < 2; tt++) {
    const int q0 = (tt == 0 ? xs0 : xs1) * 64;
    const int qw = q0 + w * 16;

    // Q fragments: A[m=l16][k=quad*8+j]
    s16x8 qf[6];
    {
      int t = qw + l16;
      const u16* p = Qc + ((size_t)(b * T_ + t) * DM + h * HD_ + quad * 8);
#pragma unroll
      for (int f = 0; f < 4; f++) qf[f] = *(const s16x8*)(p + f * 32);
      const u16* pr = Qr + ((size_t)(b * T_ + t) * (H_ * R_) + h * R_ + quad * 8);
#pragma unroll
      for (int f = 0; f < 2; f++) qf[4 + f] = *(const s16x8*)(pr + f * 32);
    }

    f32x4 o[8];
#pragma unroll
    for (int f = 0; f < 8; f++) o[f] = zz;
    float mrow[4], lrow[4];
#pragma unroll
    for (int rg = 0; rg < 4; rg++) { mrow[rg] = -1e30f; lrow[rg] = 0.f; }

    // prefetch tile k0=0
    const u16* pk[3]; const u16* pv[2];
    s16x8 kv[3], vv[2];
#pragma unroll
    for (int r = 0; r < 3; r++) { pk[r] = kBase[r]; kv[r] = *(const s16x8*)pk[r]; }
#pragma unroll
    for (int r = 0; r < 2; r++) { pv[r] = vBase[r]; vv[r] = *(const s16x8*)pv[r]; }

    const int nk = q0 + 64;
    for (int k0 = 0; k0 < nk; k0 += 32) {
      __syncthreads();  // previous tile fully consumed
#pragma unroll
      for (int r = 0; r < 3; r++) *(s16x8*)&Kt[kLds[r]] = kv[r];
#pragma unroll
      for (int r = 0; r < 2; r++) *(s16x8*)&Vt[vLds[r]] = vv[r];
      __syncthreads();  // staging visible
      if (k0 + 32 < nk) {  // prefetch next (in flight during compute)
#pragma unroll
        for (int r = 0; r < 3; r++) { pk[r] += kStep[r]; kv[r] = *(const s16x8*)pk[r]; }
#pragma unroll
        for (int r = 0; r < 2; r++) { pv[r] += 32; vv[r] = *(const s16x8*)pv[r]; }
      }

      if (k0 <= qw + 15) {  // wave-uniform
        f32x4 s[2];
        s[0] = zz; s[1] = zz;
#pragma unroll
        for (int fk = 0; fk < 2; fk++)
#pragma unroll
          for (int e = 0; e < 6; e++) {
            s16x8 kf = *(const s16x8*)&Kt[(fk * 16 + l16) * KT_S + e * 32 + quad * 8];
            s[fk] = __builtin_amdgcn_mfma_f32_16x16x32_bf16(qf[e], kf, s[fk], 0, 0, 0);
          }
        // online softmax, base-2 domain; C row=quad*4+rg, col=k0+fk*16+l16
#pragma unroll
        for (int rg = 0; rg < 4; rg++) {
          int q = qw + quad * 4 + rg;
          float s0 = s[0][rg] * SCALE2; if (k0 + l16 > q) s0 = -1e30f;
          float s1 = s[1][rg] * SCALE2; if (k0 + 16 + l16 > q) s1 = -1e30f;
          float mx = fmaxf(s0, s1);
          mx = fmaxf(mx, __shfl_xor(mx, 1));
          mx = fmaxf(mx, __shfl_xor(mx, 2));
          mx = fmaxf(mx, __shfl_xor(mx, 4));
          mx = fmaxf(mx, __shfl_xor(mx, 8));
          float mn = fmaxf(mrow[rg], mx);
          float e0 = exp2f(s0 - mn);
          float e1 = exp2f(s1 - mn);
          float rs = e0 + e1;
          rs += __shfl_xor(rs, 1);
          rs += __shfl_xor(rs, 2);
          rs += __shfl_xor(rs, 4);
          rs += __shfl_xor(rs, 8);
          float alpha = exp2f(mrow[rg] - mn);
          lrow[rg] = lrow[rg] * alpha + rs;
          mrow[rg] = mn;
#pragma unroll
          for (int f = 0; f < 8; f++) o[f][rg] *= alpha;
          Ps[w][(quad * 4 + rg) * VT_S + l16] = f2b(e0);
          Ps[w][(quad * 4 + rg) * VT_S + 16 + l16] = f2b(e1);
        }
        __asm__ volatile("s_waitcnt lgkmcnt(0)" ::: "memory");  // per-wave Ps write->read
        s16x8 pa = *(const s16x8*)&Ps[w][l16 * VT_S + quad * 8];
#pragma unroll
        for (int f = 0; f < 8; f++) {
          s16x8 vb = *(const s16x8*)&Vt[(f * 16 + l16) * VT_S + quad * 8];
          o[f] = __builtin_amdgcn_mfma_f32_16x16x32_bf16(pa, vb, o[f], 0, 0, 0);
        }
      }
    }

#pragma unroll
    for (int f = 0; f < 8; f++) {
#pragma unroll
      for (int rg = 0; rg < 4; rg++) {
        int q = qw + quad * 4 + rg;
        float v = o[f][rg] / lrow[rg];
        O[(size_t)(b * T_ + q) * DM + h * HD_ + f * 16 + l16] = f2b(v);
      }
    }
    __syncthreads();  // tile B staging must not race tile A's last reads
  }
}

// ---------------- launch ----------------
extern "C" void kernel_launch(void* const* d_in, const int* in_sizes, int n_in,
                              void* d_out, int out_size, void* d_ws, size_t ws_size,
                              hipStream_t stream) {
  const float* x    = (const float*)d_in[0];
  const float* fr   = (const float*)d_in[1];
  const float* wdkv = (const float*)d_in[2];
  const float* wuk  = (const float*)d_in[3];
  const float* wuv  = (const float*)d_in[4];
  const float* wkr  = (const float*)d_in[5];
  const float* wdq  = (const float*)d_in[6];
  const float* wuq  = (const float*)d_in[7];
  const float* wqr  = (const float*)d_in[8];
  const float* wo   = (const float*)d_in[9];
  u16* ws = (u16*)d_ws;

  const int M1 = 1048576;
  u16* x_bf  = ws;                 // 8M  (dead after c_Q gemm) -> Om overlays
  u16* Om    = ws;                 // 8M  [flash..final gemm]
  u16* Kc    = ws + 8 * M1;        // 8M  (b,t,h*hd)
  u16* VTm   = ws + 16 * M1;       // 8M  (b,h*hd,t)
  u16* Qc    = ws + 24 * M1;       // 8M  (b,t,h*hd)
  u16* Qr    = ws + 32 * M1;       // 4M  (b,t,h,r)
  u16* W     = ws + 36 * M1;       // 4M  weight-transpose slot (serial reuse)
  u16* cKV   = ws + 40 * M1;       // 2M
  u16* cQ    = ws + 42 * M1;       // 4M
  u16* xKR   = ws + 46 * M1;       // 262144
  u16* fr_bf = xKR + 262144;       // 65536
  u16* kr_bf = fr_bf + 65536;      // 262144

  float* out_y   = (float*)d_out;              // (b,t,2048)
  float* out_ckv = (float*)d_out + 8388608;    // (b,t,512)
  float* out_kr  = (float*)d_out + 10485760;   // (b,t,64)
  (void)in_sizes; (void)n_in; (void)out_size; (void)ws_size;

  dim3 blk(256);

  conv_k<<<dim3(8192), blk, 0, stream>>>(x, x_bf, 8388608);
  conv_k<<<dim3(64), blk, 0, stream>>>(fr, fr_bf, 65536);

  // c_KV = x @ W_DKV  (bf16 ws + fp32 out)
  transpose_k<<<dim3(8, 32), blk, 0, stream>>>(wdkv, W, 2048, 512);
  gemm_bf16<3><<<dim3(4, 32), blk, 0, stream>>>(x_bf, W, cKV, out_ckv, 4096, 512, 2048);
  // K_c = c_KV @ W_UK
  transpose_k<<<dim3(32, 8), blk, 0, stream>>>(wuk, W, 512, 2048);
  gemm_bf16<0><<<dim3(16, 32), blk, 0, stream>>>(cKV, W, Kc, nullptr, 4096, 2048, 512);
  // V^T = (c_KV @ W_UV)^T  (stored (b,h,hd,t))
  transpose_k<<<dim3(32, 8), blk, 0, stream>>>(wuv, W, 512, 2048);
  gemm_bf16<1><<<dim3(16, 32), blk, 0, stream>>>(cKV, W, VTm, nullptr, 4096, 2048, 512);
  // K_r = rope(x @ W_KR)  (bf16 ws + fp32 out)
  transpose_k<<<dim3(1, 32), blk, 0, stream>>>(wkr, W, 2048, 64);
  gemm_bf16<0><<<dim3(1, 32), blk, 0, stream>>>(x_bf, W, xKR, nullptr, 4096, 64, 2048);
  rope_k<<<dim3(512), blk, 0, stream>>>(xKR, fr_bf, kr_bf, out_kr);
  // c_Q = x @ W_DQ
  transpose_k<<<dim3(16, 32), blk, 0, stream>>>(wdq, W, 2048, 1024);
  gemm_bf16<0><<<dim3(8, 32), blk, 0, stream>>>(x_bf, W, cQ, nullptr, 4096, 1024, 2048);
  // Q_c = c_Q @ W_UQ
  transpose_k<<<dim3(32, 16), blk, 0, stream>>>(wuq, W, 1024, 2048);
  gemm_bf16<0><<<dim3(16, 32), blk, 0, stream>>>(cQ, W, Qc, nullptr, 4096, 2048, 1024);
  // Q_r = rope(c_Q @ W_QR)
  transpose_k<<<dim3(16, 16), blk, 0, stream>>>(wqr, W, 1024, 1024);
  gemm_bf16<0><<<dim3(8, 32), blk, 0, stream>>>(cQ, W, Qr, nullptr, 4096, 1024, 1024);
  rope_q<<<dim3(8192), blk, 0, stream>>>(Qr, fr_bf);
  // attention (Om overlays dead x_bf region); paired q-tiles -> grid.x = 16
  flash_attn<<<dim3(16, 32), blk, 0, stream>>>(Qc, Qr, Kc, kr_bf, VTm, Om);
  // y = attn_out @ W_O  (fp32 out)
  transpose_k<<<dim3(32, 32), blk, 0, stream>>>(wo, W, 2048, 2048);
  gemm_bf16<2><<<dim3(16, 32), blk, 0, stream>>>(Om, W, nullptr, out_y, 4096, 2048, 2048);
}

// Round 6
// 462.799 us; speedup vs baseline: 1.6626x; 1.3158x over previous
//
#include <hip/hip_runtime.h>
#include <stdint.h>

typedef unsigned short u16;
typedef __attribute__((ext_vector_type(8))) short s16x8;
typedef __attribute__((ext_vector_type(4))) float f32x4;

#define B_   2
#define T_   2048
#define DM   2048
#define H_   16
#define HD_  128
#define R_   64
#define E_   192
// 1/sqrt(192) * log2(e): softmax in base-2 domain
#define SCALE2 0.104117542f

__device__ __forceinline__ u16 f2b(float f) {
  union { float f; uint32_t u; } x; x.f = f;
  uint32_t u = x.u;
  return (u16)((u + 0x7FFFu + ((u >> 16) & 1u)) >> 16);  // RNE
}
__device__ __forceinline__ float b2f(u16 h) {
  union { uint32_t u; float f; } x; x.u = ((uint32_t)h) << 16;
  return x.f;
}
// async global->LDS, 16B/lane; LDS dest = wave-uniform base + lane*16
__device__ __forceinline__ void ld_lds16(const void* g, void* l) {
  __builtin_amdgcn_global_load_lds((const __attribute__((address_space(1))) void*)g,
                                   (__attribute__((address_space(3))) void*)l,
                                   16, 0, 0);
}

// ---------- input convert fp32 -> bf16 ----------
__global__ __launch_bounds__(256) void conv_k(const float* __restrict__ in, u16* __restrict__ out, int n) {
  int i = blockIdx.x * 256 + threadIdx.x;
  if (i * 4 >= n) return;
  float4 v = *(const float4*)(in + i * 4);
  ushort4 o;
  o.x = f2b(v.x); o.y = f2b(v.y); o.z = f2b(v.z); o.w = f2b(v.w);
  *(ushort4*)(out + i * 4) = o;
}

// ---------- weight transpose (K,N) fp32 -> (N,K) bf16 ----------
__global__ __launch_bounds__(256) void transpose_k(const float* __restrict__ in, u16* __restrict__ out,
                                                   int K, int N) {
  __shared__ u16 t[64][65];
  int bn = blockIdx.x * 64, bk = blockIdx.y * 64;
  int tid = threadIdx.x;
  int r0 = tid >> 4, c0 = (tid & 15) * 4;
#pragma unroll
  for (int rr = 0; rr < 64; rr += 16) {
    float4 v = *(const float4*)(in + (size_t)(bk + r0 + rr) * N + bn + c0);
    t[r0 + rr][c0 + 0] = f2b(v.x); t[r0 + rr][c0 + 1] = f2b(v.y);
    t[r0 + rr][c0 + 2] = f2b(v.z); t[r0 + rr][c0 + 3] = f2b(v.w);
  }
  __syncthreads();
#pragma unroll
  for (int rr = 0; rr < 64; rr += 16) {
    ushort4 v;
    v.x = t[c0 + 0][r0 + rr]; v.y = t[c0 + 1][r0 + rr];
    v.z = t[c0 + 2][r0 + rr]; v.w = t[c0 + 3][r0 + rr];
    *(ushort4*)(out + (size_t)(bn + r0 + rr) * K + bk + c0) = v;
  }
}

// ---------------- GEMM: C(M,N) = A(M,K) * Bt(N,K)^T, bf16 in, fp32 acc ----------------
// EPI 2: fp32 OF (y).
// EPI 4: n<2048 -> O0 bf16 row-major (Kc); else V^T store to O1.
// EPI 5: n<2048 -> O0 (Qc); else O1 at width 1024 (Qr raw).
// EPI 6: n<512 -> O0 (cKV) + OF fp32 (out_ckv); n<576 -> O1 width 64 (xKR); n<1600 -> O2 width 1024 (cQ).
template <int EPI>
__global__ __launch_bounds__(256)
void gemm_bf16(const u16* __restrict__ A, const u16* __restrict__ Bt,
               u16* __restrict__ O0, u16* __restrict__ O1, u16* __restrict__ O2,
               float* __restrict__ OF, int M, int N, int K) {
  __shared__ __align__(16) u16 Al[128 * 32];
  __shared__ __align__(16) u16 Bl[128 * 32];
  const int tid = threadIdx.x;
  const int ln = tid & 63, w = tid >> 6;
  const int quad = ln >> 4, l16 = ln & 15;
  const int wm = (w >> 1) * 64, wn = (w & 1) * 64;
  const int m0 = blockIdx.y * 128, n0 = blockIdx.x * 128;

  f32x4 zz = {0.f, 0.f, 0.f, 0.f};
  f32x4 acc[4][4];
#pragma unroll
  for (int i = 0; i < 4; i++)
#pragma unroll
    for (int j = 0; j < 4; j++) acc[i][j] = zz;

  const u16* aG[2];
  const u16* bG[2];
  int ldsC[2];
#pragma unroll
  for (int r = 0; r < 2; r++) {
    int i = tid + r * 256;
    int row = i >> 2, cq = (i & 3) * 8;
    aG[r] = A + (size_t)(m0 + row) * K + cq;
    int rb = n0 + row;
    if (rb > N - 1) rb = N - 1;  // clamp for partial tiles (dup rows, cols discarded)
    bG[r] = Bt + (size_t)rb * K + cq;
    ldsC[r] = ((tid & ~63) + r * 256) * 8;  // wave-uniform chunk base (shorts)
  }

  for (int k = 0; k < K; k += 32) {
#pragma unroll
    for (int r = 0; r < 2; r++) {
      ld_lds16(aG[r] + k, &Al[ldsC[r]]);
      ld_lds16(bG[r] + k, &Bl[ldsC[r]]);
    }
    __syncthreads();
    s16x8 af[4], bf[4];
#pragma unroll
    for (int f = 0; f < 4; f++)
      af[f] = *(const s16x8*)&Al[(wm + f * 16 + l16) * 32 + quad * 8];
#pragma unroll
    for (int f = 0; f < 4; f++)
      bf[f] = *(const s16x8*)&Bl[(wn + f * 16 + l16) * 32 + quad * 8];
#pragma unroll
    for (int i = 0; i < 4; i++)
#pragma unroll
      for (int j = 0; j < 4; j++)
        acc[i][j] = __builtin_amdgcn_mfma_f32_16x16x32_bf16(af[i], bf[j], acc[i][j], 0, 0, 0);
    __syncthreads();
  }

#pragma unroll
  for (int fm = 0; fm < 4; fm++) {
#pragma unroll
    for (int fn = 0; fn < 4; fn++) {
      int n = n0 + wn + fn * 16 + l16;
      int mb = m0 + wm + fm * 16 + quad * 4;
      if (EPI == 2) {
        if (n < N) {
#pragma unroll
          for (int rg = 0; rg < 4; rg++) OF[(size_t)(mb + rg) * N + n] = acc[fm][fn][rg];
        }
      } else if (EPI == 4) {
        if (n < 2048) {
#pragma unroll
          for (int rg = 0; rg < 4; rg++) O0[(size_t)(mb + rg) * 2048 + n] = f2b(acc[fm][fn][rg]);
        } else {
          int hd = n - 2048, b = mb >> 11, t = mb & 2047;
          ushort4 v;
          v.x = f2b(acc[fm][fn][0]); v.y = f2b(acc[fm][fn][1]);
          v.z = f2b(acc[fm][fn][2]); v.w = f2b(acc[fm][fn][3]);
          *(ushort4*)(O1 + ((size_t)(b * 2048 + hd) * 2048 + t)) = v;
        }
      } else if (EPI == 5) {
        if (n < 2048) {
#pragma unroll
          for (int rg = 0; rg < 4; rg++) O0[(size_t)(mb + rg) * 2048 + n] = f2b(acc[fm][fn][rg]);
        } else {
#pragma unroll
          for (int rg = 0; rg < 4; rg++) O1[(size_t)(mb + rg) * 1024 + (n - 2048)] = f2b(acc[fm][fn][rg]);
        }
      } else {  // EPI 6
        if (n < 512) {
#pragma unroll
          for (int rg = 0; rg < 4; rg++) {
            float v = acc[fm][fn][rg];
            O0[(size_t)(mb + rg) * 512 + n] = f2b(v);
            OF[(size_t)(mb + rg) * 512 + n] = v;
          }
        } else if (n < 576) {
#pragma unroll
          for (int rg = 0; rg < 4; rg++) O1[(size_t)(mb + rg) * 64 + (n - 512)] = f2b(acc[fm][fn][rg]);
        } else if (n < 1600) {
#pragma unroll
          for (int rg = 0; rg < 4; rg++) O2[(size_t)(mb + rg) * 1024 + (n - 576)] = f2b(acc[fm][fn][rg]);
        }
      }
    }
  }
}

// ---------------- RoPE (K side; Q rope fused into flash) ----------------
__global__ __launch_bounds__(256) void rope_k(const u16* __restrict__ in, const u16* __restrict__ fr,
                                              u16* __restrict__ out_ws, float* __restrict__ out_io) {
  int i = blockIdx.x * 256 + threadIdx.x;  // pair index over (b,t,32)
  int r2 = i & 31, t = (i >> 5) & (T_ - 1);
  float x0 = b2f(in[2 * i]), x1 = b2f(in[2 * i + 1]);
  float a = b2f(fr[t * 32 + r2]);
  float sn, cs;
  __sincosf(a, &sn, &cs);
  float y0 = x0 * cs - x1 * sn, y1 = x0 * sn + x1 * cs;
  out_ws[2 * i] = f2b(y0); out_ws[2 * i + 1] = f2b(y1);
  out_io[2 * i] = y0; out_io[2 * i + 1] = y1;
}

// ---------------- flash attention (S^T formulation) ----------------
// grid (bh=32, qpair=16): same-bh blocks share an XCD (id%8 == bh%8) for KV L2 locality.
// Wave computes S^T (keys x q): row-reduce = 7 in-lane + 2 shuffles. Row-sums via
// ones-rows appended to Vt (MFMA computes l alongside O). Q rope applied at load.
#define KT_S 200
#define VT_S 40
#define PS_S 40
__global__ __launch_bounds__(256)
void flash_attn(const u16* __restrict__ Qc, const u16* __restrict__ Qr,
                const u16* __restrict__ Kc, const u16* __restrict__ Kr,
                const u16* __restrict__ VT, const u16* __restrict__ fr,
                u16* __restrict__ O) {
  __shared__ __align__(16) u16 Kt[32 * KT_S];      // [key][e]
  __shared__ __align__(16) u16 Vt[144 * VT_S];     // [hd + 16 ones rows][key]
  __shared__ __align__(16) u16 Ps[4][16 * PS_S];   // per-wave [q][key]

  const int tid = threadIdx.x;
  const int ln = tid & 63, w = tid >> 6;
  const int quad = ln >> 4, l16 = ln & 15;
  const int bh = blockIdx.x, b = bh >> 4, h = bh & 15;

  // ones rows 128..143 (row-sum trick); written once, never restaged
  for (int i = tid; i < 512; i += 256) Vt[(128 + (i >> 5)) * VT_S + (i & 31)] = 0x3F80;

  // staging maps (tile-invariant)
  const u16* kBase[3]; int kStep[3], kLds[3];
#pragma unroll
  for (int r = 0; r < 3; r++) {
    int i = tid + r * 256;
    int key = i / 24, c = i - key * 24;
    kLds[r] = key * KT_S + c * 8;
    if (c < 16) { kBase[r] = Kc + ((size_t)(b * T_ + key) * DM + h * HD_ + c * 8); kStep[r] = 32 * DM; }
    else        { kBase[r] = Kr + ((size_t)(b * T_ + key) * R_ + (c - 16) * 8);    kStep[r] = 32 * R_; }
  }
  const u16* vBase[2]; int vLds[2];
#pragma unroll
  for (int r = 0; r < 2; r++) {
    int i = tid + r * 256;
    vLds[r] = (i >> 2) * VT_S + (i & 3) * 8;
    vBase[r] = VT + ((size_t)(bh * HD_ + (i >> 2)) * T_ + (i & 3) * 8);
  }

  f32x4 zz = {0.f, 0.f, 0.f, 0.f};
  const int xs0 = blockIdx.y, xs1 = 31 - (int)blockIdx.y;

  for (int tt = 0; tt < 2; tt++) {
    const int q0 = (tt ? xs1 : xs0) * 64;
    const int qw = q0 + w * 16;

    // Q fragments (B-operand layout: n=l16 (q), k=quad*8+j (e)); rope fused for e>=128
    s16x8 qf[6];
    {
      int t = qw + l16;
      const u16* p = Qc + ((size_t)(b * T_ + t) * DM + h * HD_ + quad * 8);
#pragma unroll
      for (int f = 0; f < 4; f++) qf[f] = *(const s16x8*)(p + f * 32);
      const u16* pr = Qr + ((size_t)(b * T_ + t) * (H_ * R_) + h * R_ + quad * 8);
#pragma unroll
      for (int half = 0; half < 2; half++) {
        s16x8 v = *(const s16x8*)(pr + half * 32);
        s16x8 o2;
#pragma unroll
        for (int p2 = 0; p2 < 4; p2++) {
          float a = b2f(fr[t * 32 + half * 16 + quad * 4 + p2]);
          float sn, cs;
          __sincosf(a, &sn, &cs);
          float x0 = b2f((u16)v[2 * p2]), x1 = b2f((u16)v[2 * p2 + 1]);
          o2[2 * p2] = (short)f2b(x0 * cs - x1 * sn);
          o2[2 * p2 + 1] = (short)f2b(x0 * sn + x1 * cs);
        }
        qf[4 + half] = o2;
      }
    }

    f32x4 o[9];
#pragma unroll
    for (int f = 0; f < 9; f++) o[f] = zz;
    float mL = -1e30f;  // running max for q = qw + l16

    // prefetch tile k0=0
    const u16* pk[3]; const u16* pv[2];
    s16x8 kv[3], vv[2];
#pragma unroll
    for (int r = 0; r < 3; r++) { pk[r] = kBase[r]; kv[r] = *(const s16x8*)pk[r]; }
#pragma unroll
    for (int r = 0; r < 2; r++) { pv[r] = vBase[r]; vv[r] = *(const s16x8*)pv[r]; }

    const int nk = q0 + 64;
    for (int k0 = 0; k0 < nk; k0 += 32) {
      __syncthreads();  // previous tile fully consumed (also covers tt transition)
#pragma unroll
      for (int r = 0; r < 3; r++) *(s16x8*)&Kt[kLds[r]] = kv[r];
#pragma unroll
      for (int r = 0; r < 2; r++) *(s16x8*)&Vt[vLds[r]] = vv[r];
      __syncthreads();  // staging visible
      if (k0 + 32 < nk) {
#pragma unroll
        for (int r = 0; r < 3; r++) { pk[r] += kStep[r]; kv[r] = *(const s16x8*)pk[r]; }
#pragma unroll
        for (int r = 0; r < 2; r++) { pv[r] += 32; vv[r] = *(const s16x8*)pv[r]; }
      }

      if (k0 <= qw + 15) {  // wave-uniform
        // S^T = K * Q^T : A-frag = K rows (keys), B-frag = Q
        f32x4 s0 = zz, s1 = zz;
#pragma unroll
        for (int e = 0; e < 6; e++) {
          s16x8 kf0 = *(const s16x8*)&Kt[l16 * KT_S + e * 32 + quad * 8];
          s16x8 kf1 = *(const s16x8*)&Kt[(16 + l16) * KT_S + e * 32 + quad * 8];
          s0 = __builtin_amdgcn_mfma_f32_16x16x32_bf16(kf0, qf[e], s0, 0, 0, 0);
          s1 = __builtin_amdgcn_mfma_f32_16x16x32_bf16(kf1, qf[e], s1, 0, 0, 0);
        }
        // lane holds S^T[key = k0 + fk*16 + quad*4 + rg][q = qw + l16]
        const int q = qw + l16;
        float sv[8];
#pragma unroll
        for (int rg = 0; rg < 4; rg++) {
          int key0 = k0 + quad * 4 + rg;
          sv[rg]     = (key0 > q)      ? -1e30f : s0[rg] * SCALE2;
          sv[4 + rg] = (key0 + 16 > q) ? -1e30f : s1[rg] * SCALE2;
        }
        float mx = sv[0];
#pragma unroll
        for (int j = 1; j < 8; j++) mx = fmaxf(mx, sv[j]);
        mx = fmaxf(mx, __shfl_xor(mx, 16));
        mx = fmaxf(mx, __shfl_xor(mx, 32));
        float mn = fmaxf(mL, mx);
        float alpha = exp2f(mL - mn);
        mL = mn;
        ushort4 p0, p1;
        p0.x = f2b(exp2f(sv[0] - mn)); p0.y = f2b(exp2f(sv[1] - mn));
        p0.z = f2b(exp2f(sv[2] - mn)); p0.w = f2b(exp2f(sv[3] - mn));
        p1.x = f2b(exp2f(sv[4] - mn)); p1.y = f2b(exp2f(sv[5] - mn));
        p1.z = f2b(exp2f(sv[6] - mn)); p1.w = f2b(exp2f(sv[7] - mn));
        *(ushort4*)&Ps[w][l16 * PS_S + quad * 4] = p0;
        *(ushort4*)&Ps[w][l16 * PS_S + 16 + quad * 4] = p1;
        // broadcast alpha for O's C-layout rows (q = quad*4+rg lives in lanes l16 = quad*4+rg)
        float al[4];
#pragma unroll
        for (int rg = 0; rg < 4; rg++) al[rg] = __shfl(alpha, (ln & 48) | (quad * 4 + rg));
#pragma unroll
        for (int f = 0; f < 9; f++)
#pragma unroll
          for (int rg = 0; rg < 4; rg++) o[f][rg] *= al[rg];
        __asm__ volatile("s_waitcnt lgkmcnt(0)" ::: "memory");  // per-wave Ps write->read
        // PV: A = P (m=q=l16, k=key=quad*8+j), B = V^T rows (f=8 -> ones rows = row sums)
        s16x8 pa = *(const s16x8*)&Ps[w][l16 * PS_S + quad * 8];
#pragma unroll
        for (int f = 0; f < 9; f++) {
          s16x8 vb = *(const s16x8*)&Vt[(f * 16 + l16) * VT_S + quad * 8];
          o[f] = __builtin_amdgcn_mfma_f32_16x16x32_bf16(pa, vb, o[f], 0, 0, 0);
        }
      }
    }

    float inv[4];
#pragma unroll
    for (int rg = 0; rg < 4; rg++) inv[rg] = 1.0f / o[8][rg];  // row-sum from ones column
#pragma unroll
    for (int f = 0; f < 8; f++) {
#pragma unroll
      for (int rg = 0; rg < 4; rg++) {
        int q = qw + quad * 4 + rg;
        O[(size_t)(b * T_ + q) * DM + h * HD_ + f * 16 + l16] = f2b(o[f][rg] * inv[rg]);
      }
    }
  }
}

// ---------------- launch ----------------
extern "C" void kernel_launch(void* const* d_in, const int* in_sizes, int n_in,
                              void* d_out, int out_size, void* d_ws, size_t ws_size,
                              hipStream_t stream) {
  const float* x    = (const float*)d_in[0];
  const float* fr   = (const float*)d_in[1];
  const float* wdkv = (const float*)d_in[2];
  const float* wuk  = (const float*)d_in[3];
  const float* wuv  = (const float*)d_in[4];
  const float* wkr  = (const float*)d_in[5];
  const float* wdq  = (const float*)d_in[6];
  const float* wuq  = (const float*)d_in[7];
  const float* wqr  = (const float*)d_in[8];
  const float* wo   = (const float*)d_in[9];
  u16* ws = (u16*)d_ws;

  const int M1 = 1048576;
  u16* x_bf  = ws;                 // 8M (dead after gx) -> Om overlays
  u16* Om    = ws;                 // 8M [flash..g8]
  u16* Kc    = ws + 8 * M1;        // 8M (b,t,h*hd)
  u16* VTm   = ws + 16 * M1;       // 8M (b,h*hd,t)
  u16* Qc    = ws + 24 * M1;       // 8M (b,t,h*hd)
  u16* Qr    = ws + 32 * M1;       // 4M (b,t,h,r) RAW (rope fused in flash)
  u16* W     = ws + 36 * M1;       // 4M transpose arena (serial reuse)
  u16* cKV   = ws + 40 * M1;       // 2M
  u16* cQ    = ws + 42 * M1;       // 4M
  u16* xKR   = ws + 46 * M1;       // 262144
  u16* fr_bf = xKR + 262144;       // 65536
  u16* kr_bf = fr_bf + 65536;      // 262144

  float* out_y   = (float*)d_out;              // (b,t,2048)
  float* out_ckv = (float*)d_out + 8388608;    // (b,t,512)
  float* out_kr  = (float*)d_out + 10485760;   // (b,t,64)
  (void)in_sizes; (void)n_in; (void)out_size; (void)ws_size;

  dim3 blk(256);

  conv_k<<<dim3(8192), blk, 0, stream>>>(x, x_bf, 8388608);
  conv_k<<<dim3(64), blk, 0, stream>>>(fr, fr_bf, 65536);

  // ---- gx: [cKV | xKR | cQ] = x @ [W_DKV | W_KR | W_DQ], N=1600, K=2048 ----
  transpose_k<<<dim3(8, 32), blk, 0, stream>>>(wdkv, W, 2048, 512);
  transpose_k<<<dim3(1, 32), blk, 0, stream>>>(wkr, W + 512 * 2048, 2048, 64);
  transpose_k<<<dim3(16, 32), blk, 0, stream>>>(wdq, W + 576 * 2048, 2048, 1024);
  gemm_bf16<6><<<dim3(13, 32), blk, 0, stream>>>(x_bf, W, cKV, xKR, cQ, out_ckv, 4096, 1600, 2048);
  rope_k<<<dim3(512), blk, 0, stream>>>(xKR, fr_bf, kr_bf, out_kr);

  // ---- gkv: [K_c | V^T] = c_KV @ [W_UK | W_UV], N=4096, K=512 ----
  transpose_k<<<dim3(32, 8), blk, 0, stream>>>(wuk, W, 512, 2048);
  transpose_k<<<dim3(32, 8), blk, 0, stream>>>(wuv, W + 2048 * 512, 512, 2048);
  gemm_bf16<4><<<dim3(32, 32), blk, 0, stream>>>(cKV, W, Kc, VTm, nullptr, nullptr, 4096, 4096, 512);

  // ---- gq: [Q_c | Q_r-raw] = c_Q @ [W_UQ | W_QR], N=3072, K=1024 ----
  transpose_k<<<dim3(32, 16), blk, 0, stream>>>(wuq, W, 1024, 2048);
  transpose_k<<<dim3(16, 16), blk, 0, stream>>>(wqr, W + 2048 * 1024, 1024, 1024);
  gemm_bf16<5><<<dim3(24, 32), blk, 0, stream>>>(cQ, W, Qc, Qr, nullptr, nullptr, 4096, 3072, 1024);

  // ---- attention (Om overlays dead x_bf) ----
  flash_attn<<<dim3(32, 16), blk, 0, stream>>>(Qc, Qr, Kc, kr_bf, VTm, fr_bf, Om);

  // ---- y = attn_out @ W_O ----
  transpose_k<<<dim3(32, 32), blk, 0, stream>>>(wo, W, 2048, 2048);
  gemm_bf16<2><<<dim3(16, 32), blk, 0, stream>>>(Om, W, nullptr, nullptr, nullptr, out_y, 4096, 2048, 2048);
}

// Round 7
// 423.459 us; speedup vs baseline: 1.8171x; 1.0929x over previous
//
#include <hip/hip_runtime.h>
#include <stdint.h>

typedef unsigned short u16;
typedef __attribute__((ext_vector_type(8))) short s16x8;
typedef __attribute__((ext_vector_type(4))) float f32x4;

#define B_   2
#define T_   2048
#define DM   2048
#define H_   16
#define HD_  128
#define R_   64
#define E_   192
// 1/sqrt(192) * log2(e): softmax in base-2 domain
#define SCALE2 0.104117542f

__device__ __forceinline__ u16 f2b(float f) {
  union { float f; uint32_t u; } x; x.f = f;
  uint32_t u = x.u;
  return (u16)((u + 0x7FFFu + ((u >> 16) & 1u)) >> 16);  // RNE
}
__device__ __forceinline__ float b2f(u16 h) {
  union { uint32_t u; float f; } x; x.u = ((uint32_t)h) << 16;
  return x.f;
}
// pack two f32 -> two bf16 (truncation; used only for P which is renormalized by row-sum)
__device__ __forceinline__ unsigned pk2(float a, float b) {
  union { float f; unsigned u; } A, B; A.f = a; B.f = b;
  return (B.u & 0xFFFF0000u) | (A.u >> 16);
}
// async global->LDS, 16B/lane; LDS dest = wave-uniform base + lane*16
__device__ __forceinline__ void ld_lds16(const void* g, void* l) {
  __builtin_amdgcn_global_load_lds((const __attribute__((address_space(1))) void*)g,
                                   (__attribute__((address_space(3))) void*)l,
                                   16, 0, 0);
}

// ---------- device helpers: conv + 64x64 transpose tile ----------
__device__ __forceinline__ void conv_dev(const float* __restrict__ in, u16* __restrict__ out, int i) {
  float4 v = *(const float4*)(in + (size_t)i * 4);
  ushort4 o;
  o.x = f2b(v.x); o.y = f2b(v.y); o.z = f2b(v.z); o.w = f2b(v.w);
  *(ushort4*)(out + (size_t)i * 4) = o;
}
__device__ __forceinline__ void tr64(const float* __restrict__ in, u16* __restrict__ out,
                                     int K, int N, int bx, int by) {
  __shared__ u16 t[64][65];
  int bn = bx * 64, bk = by * 64;
  int tid = threadIdx.x;
  int r0 = tid >> 4, c0 = (tid & 15) * 4;
#pragma unroll
  for (int rr = 0; rr < 64; rr += 16) {
    float4 v = *(const float4*)(in + (size_t)(bk + r0 + rr) * N + bn + c0);
    t[r0 + rr][c0 + 0] = f2b(v.x); t[r0 + rr][c0 + 1] = f2b(v.y);
    t[r0 + rr][c0 + 2] = f2b(v.z); t[r0 + rr][c0 + 3] = f2b(v.w);
  }
  __syncthreads();
#pragma unroll
  for (int rr = 0; rr < 64; rr += 16) {
    ushort4 v;
    v.x = t[c0 + 0][r0 + rr]; v.y = t[c0 + 1][r0 + rr];
    v.z = t[c0 + 2][r0 + rr]; v.w = t[c0 + 3][r0 + rr];
    *(ushort4*)(out + (size_t)(bn + r0 + rr) * K + bk + c0) = v;
  }
}

// ---------- TA: conv x, conv fr, transpose {W_DKV, W_KR, W_DQ} into gx arena ----------
__global__ __launch_bounds__(256)
void ta_k(const float* __restrict__ x, const float* __restrict__ fr,
          u16* __restrict__ x_bf, u16* __restrict__ fr_bf,
          const float* __restrict__ wdkv, const float* __restrict__ wkr,
          const float* __restrict__ wdq, u16* __restrict__ W) {
  int id = blockIdx.x;
  if (id < 8192)        conv_dev(x, x_bf, id * 256 + threadIdx.x);
  else if (id < 8256)   conv_dev(fr, fr_bf, (id - 8192) * 256 + threadIdx.x);
  else if (id < 8512) { int i = id - 8256; tr64(wdkv, W, 2048, 512, i & 7, i >> 3); }
  else if (id < 8544) { int i = id - 8512; tr64(wkr, W + 512 * 2048, 2048, 64, 0, i); }
  else                { int i = id - 8544; tr64(wdq, W + 576 * 2048, 2048, 1024, i & 15, i >> 4); }
}
// ---------- TB1: {W_UK, W_UV} ----------
__global__ __launch_bounds__(256)
void tb1_k(const float* __restrict__ wuk, const float* __restrict__ wuv, u16* __restrict__ W) {
  int id = blockIdx.x;
  if (id < 256) tr64(wuk, W, 512, 2048, id & 31, id >> 5);
  else { int i = id - 256; tr64(wuv, W + 2048 * 512, 512, 2048, i & 31, i >> 5); }
}
// ---------- TB2: {W_UQ, W_QR} ----------
__global__ __launch_bounds__(256)
void tb2_k(const float* __restrict__ wuq, const float* __restrict__ wqr, u16* __restrict__ W) {
  int id = blockIdx.x;
  if (id < 512) tr64(wuq, W, 1024, 2048, id & 31, id >> 5);
  else { int i = id - 512; tr64(wqr, W + 2048 * 1024, 1024, 1024, i & 15, i >> 4); }
}
// ---------- TC: W_O ----------
__global__ __launch_bounds__(256)
void tc_k(const float* __restrict__ wo, u16* __restrict__ W) {
  tr64(wo, W, 2048, 2048, blockIdx.x & 31, blockIdx.x >> 5);
}

// ---------------- GEMM: C(M,N) = A(M,K) * Bt(N,K)^T, bf16 in, fp32 acc ----------------
// EPI 2: fp32 OF (y).
// EPI 4: n<2048 -> O0 bf16 (Kc); else V^T store to O1.
// EPI 5: n<2048 -> O0 (Qc); else O1 width 1024 (Qr raw).
// EPI 6: n<512 -> O0 (cKV) + OF fp32 (out_ckv); n<576 -> fused K-rope -> O1 bf16 (kr) + OF2 fp32;
//        n<1600 -> O2 width 1024 (cQ).
template <int EPI>
__global__ __launch_bounds__(256)
void gemm_bf16(const u16* __restrict__ A, const u16* __restrict__ Bt,
               u16* __restrict__ O0, u16* __restrict__ O1, u16* __restrict__ O2,
               float* __restrict__ OF, float* __restrict__ OF2,
               const u16* __restrict__ FR, int M, int N, int K) {
  __shared__ __align__(16) u16 Al[128 * 32];
  __shared__ __align__(16) u16 Bl[128 * 32];
  const int tid = threadIdx.x;
  const int ln = tid & 63, w = tid >> 6;
  const int quad = ln >> 4, l16 = ln & 15;
  const int wm = (w >> 1) * 64, wn = (w & 1) * 64;
  const int m0 = blockIdx.y * 128, n0 = blockIdx.x * 128;

  f32x4 zz = {0.f, 0.f, 0.f, 0.f};
  f32x4 acc[4][4];
#pragma unroll
  for (int i = 0; i < 4; i++)
#pragma unroll
    for (int j = 0; j < 4; j++) acc[i][j] = zz;

  const u16* aG[2];
  const u16* bG[2];
  int ldsC[2];
#pragma unroll
  for (int r = 0; r < 2; r++) {
    int i = tid + r * 256;
    int row = i >> 2, cq = (i & 3) * 8;
    aG[r] = A + (size_t)(m0 + row) * K + cq;
    int rb = n0 + row;
    if (rb > N - 1) rb = N - 1;  // clamp for partial tiles (dup rows, cols discarded)
    bG[r] = Bt + (size_t)rb * K + cq;
    ldsC[r] = ((tid & ~63) + r * 256) * 8;  // wave-uniform chunk base (shorts)
  }

  for (int k = 0; k < K; k += 32) {
#pragma unroll
    for (int r = 0; r < 2; r++) {
      ld_lds16(aG[r] + k, &Al[ldsC[r]]);
      ld_lds16(bG[r] + k, &Bl[ldsC[r]]);
    }
    __syncthreads();
    s16x8 af[4], bf[4];
#pragma unroll
    for (int f = 0; f < 4; f++)
      af[f] = *(const s16x8*)&Al[(wm + f * 16 + l16) * 32 + quad * 8];
#pragma unroll
    for (int f = 0; f < 4; f++)
      bf[f] = *(const s16x8*)&Bl[(wn + f * 16 + l16) * 32 + quad * 8];
#pragma unroll
    for (int i = 0; i < 4; i++)
#pragma unroll
      for (int j = 0; j < 4; j++)
        acc[i][j] = __builtin_amdgcn_mfma_f32_16x16x32_bf16(af[i], bf[j], acc[i][j], 0, 0, 0);
    __syncthreads();
  }

#pragma unroll
  for (int fm = 0; fm < 4; fm++) {
#pragma unroll
    for (int fn = 0; fn < 4; fn++) {
      int n = n0 + wn + fn * 16 + l16;
      int mb = m0 + wm + fm * 16 + quad * 4;
      if (EPI == 2) {
        if (n < N) {
#pragma unroll
          for (int rg = 0; rg < 4; rg++) OF[(size_t)(mb + rg) * N + n] = acc[fm][fn][rg];
        }
      } else if (EPI == 4) {
        if (n < 2048) {
#pragma unroll
          for (int rg = 0; rg < 4; rg++) O0[(size_t)(mb + rg) * 2048 + n] = f2b(acc[fm][fn][rg]);
        } else {
          int hd = n - 2048, b = mb >> 11, t = mb & 2047;
          ushort4 v;
          v.x = f2b(acc[fm][fn][0]); v.y = f2b(acc[fm][fn][1]);
          v.z = f2b(acc[fm][fn][2]); v.w = f2b(acc[fm][fn][3]);
          *(ushort4*)(O1 + ((size_t)(b * 2048 + hd) * 2048 + t)) = v;
        }
      } else if (EPI == 5) {
        if (n < 2048) {
#pragma unroll
          for (int rg = 0; rg < 4; rg++) O0[(size_t)(mb + rg) * 2048 + n] = f2b(acc[fm][fn][rg]);
        } else {
#pragma unroll
          for (int rg = 0; rg < 4; rg++) O1[(size_t)(mb + rg) * 1024 + (n - 2048)] = f2b(acc[fm][fn][rg]);
        }
      } else {  // EPI 6
        if (n < 512) {
#pragma unroll
          for (int rg = 0; rg < 4; rg++) {
            float v = acc[fm][fn][rg];
            O0[(size_t)(mb + rg) * 512 + n] = f2b(v);
            OF[(size_t)(mb + rg) * 512 + n] = v;
          }
        } else if (n < 576) {
          // fused K-rope: adjacent lanes hold the (even,odd) pair
          int r = n - 512, r2 = r >> 1, odd = r & 1;
#pragma unroll
          for (int rg = 0; rg < 4; rg++) {
            float v = acc[fm][fn][rg];
            float p = __shfl_xor(v, 1);
            int t = mb + rg;
            float a = b2f(FR[(size_t)(t & 2047) * 32 + r2]);
            float sn, cs;
            __sincosf(a, &sn, &cs);
            float y = odd ? (p * sn + v * cs) : (v * cs - p * sn);
            O1[(size_t)t * 64 + r] = f2b(y);
            OF2[(size_t)t * 64 + r] = y;
          }
        } else if (n < 1600) {
#pragma unroll
          for (int rg = 0; rg < 4; rg++) O2[(size_t)(mb + rg) * 1024 + (n - 576)] = f2b(acc[fm][fn][rg]);
        }
      }
    }
  }
}

// ---------------- flash attention (S^T formulation, 64-key tiles) ----------------
// grid (bh=32, qpair=16): same-bh blocks share an XCD for KV L2 locality.
// 64-key staging tiles halve per-key softmax fixed costs; skip-rescale drops
// alpha/rescale work on ~90% of iterations; P packed by truncation.
#define KT_S 200  // 64 keys x 192e (+pad): 100 dwords = 4 mod 32 -> 2-way reads (free)
#define VT_S 72   // 144 rows x 64 keys (+pad): 36 dwords
#define PS_S 72
__global__ __launch_bounds__(256, 2)
void flash_attn(const u16* __restrict__ Qc, const u16* __restrict__ Qr,
                const u16* __restrict__ Kc, const u16* __restrict__ Kr,
                const u16* __restrict__ VT, const u16* __restrict__ fr,
                u16* __restrict__ O) {
  __shared__ __align__(16) u16 Kt[64 * KT_S];      // 25.6 KB [key][e]
  __shared__ __align__(16) u16 Vt[144 * VT_S];     // 20.7 KB [hd + 16 ones rows][key]
  __shared__ __align__(16) u16 Ps[4][16 * PS_S];   //  9.2 KB per-wave [q][key]

  const int tid = threadIdx.x;
  const int ln = tid & 63, w = tid >> 6;
  const int quad = ln >> 4, l16 = ln & 15;
  const int bh = blockIdx.x, b = bh >> 4, h = bh & 15;

  // ones rows 128..143 (row-sum trick); written once
  for (int i = tid; i < 1024; i += 256) Vt[(128 + (i >> 6)) * VT_S + (i & 63)] = 0x3F80;

  // staging maps (tile-invariant): K = 64 keys x 24 chunks, V = 128 rows x 8 chunks
  const u16* kBase[6]; int kStep[6], kLds[6];
#pragma unroll
  for (int r = 0; r < 6; r++) {
    int i = tid + r * 256;
    int key = i / 24, c = i - key * 24;
    kLds[r] = key * KT_S + c * 8;
    if (c < 16) { kBase[r] = Kc + ((size_t)(b * T_ + key) * DM + h * HD_ + c * 8); kStep[r] = 64 * DM; }
    else        { kBase[r] = Kr + ((size_t)(b * T_ + key) * R_ + (c - 16) * 8);    kStep[r] = 64 * R_; }
  }
  const u16* vBase[4]; int vLds[4];
#pragma unroll
  for (int r = 0; r < 4; r++) {
    int i = tid + r * 256;
    vLds[r] = (i >> 3) * VT_S + (i & 7) * 8;
    vBase[r] = VT + ((size_t)(bh * HD_ + (i >> 3)) * T_ + (i & 7) * 8);
  }

  f32x4 zz = {0.f, 0.f, 0.f, 0.f};
  const int xs0 = blockIdx.y, xs1 = 31 - (int)blockIdx.y;

  for (int tt = 0; tt < 2; tt++) {
    const int q0 = (tt ? xs1 : xs0) * 64;
    const int qw = q0 + w * 16;

    // Q fragments (B-operand: n=l16 (q), k=quad*8+j (e)); rope fused for e>=128
    s16x8 qf[6];
    {
      int t = qw + l16;
      const u16* p = Qc + ((size_t)(b * T_ + t) * DM + h * HD_ + quad * 8);
#pragma unroll
      for (int f = 0; f < 4; f++) qf[f] = *(const s16x8*)(p + f * 32);
      const u16* pr = Qr + ((size_t)(b * T_ + t) * (H_ * R_) + h * R_ + quad * 8);
#pragma unroll
      for (int half = 0; half < 2; half++) {
        s16x8 v = *(const s16x8*)(pr + half * 32);
        s16x8 o2;
#pragma unroll
        for (int p2 = 0; p2 < 4; p2++) {
          float a = b2f(fr[t * 32 + half * 16 + quad * 4 + p2]);
          float sn, cs;
          __sincosf(a, &sn, &cs);
          float x0 = b2f((u16)v[2 * p2]), x1 = b2f((u16)v[2 * p2 + 1]);
          o2[2 * p2] = (short)f2b(x0 * cs - x1 * sn);
          o2[2 * p2 + 1] = (short)f2b(x0 * sn + x1 * cs);
        }
        qf[4 + half] = o2;
      }
    }

    f32x4 o[9];
#pragma unroll
    for (int f = 0; f < 9; f++) o[f] = zz;
    float mL = -1e30f;  // running max for q = qw + l16

    // prefetch tile k0=0
    const u16* pk[6]; const u16* pv[4];
    s16x8 kv[6], vv[4];
#pragma unroll
    for (int r = 0; r < 6; r++) { pk[r] = kBase[r]; kv[r] = *(const s16x8*)pk[r]; }
#pragma unroll
    for (int r = 0; r < 4; r++) { pv[r] = vBase[r]; vv[r] = *(const s16x8*)pv[r]; }

    const int nk = q0 + 64;
    for (int k0 = 0; k0 < nk; k0 += 64) {
      __syncthreads();  // previous tile fully consumed
#pragma unroll
      for (int r = 0; r < 6; r++) *(s16x8*)&Kt[kLds[r]] = kv[r];
#pragma unroll
      for (int r = 0; r < 4; r++) *(s16x8*)&Vt[vLds[r]] = vv[r];
      __syncthreads();  // staging visible
      if (k0 + 64 < nk) {
#pragma unroll
        for (int r = 0; r < 6; r++) { pk[r] += kStep[r]; kv[r] = *(const s16x8*)pk[r]; }
#pragma unroll
        for (int r = 0; r < 4; r++) { pv[r] += 64; vv[r] = *(const s16x8*)pv[r]; }
      }

      // S^T = K * Q^T : A-frag = K rows (keys), B-frag = Q (regs)
      f32x4 s[4];
#pragma unroll
      for (int kg = 0; kg < 4; kg++) s[kg] = zz;
#pragma unroll
      for (int e = 0; e < 6; e++)
#pragma unroll
        for (int kg = 0; kg < 4; kg++) {
          s16x8 kf = *(const s16x8*)&Kt[(kg * 16 + l16) * KT_S + e * 32 + quad * 8];
          s[kg] = __builtin_amdgcn_mfma_f32_16x16x32_bf16(kf, qf[e], s[kg], 0, 0, 0);
        }
      // lane holds S^T[key = k0 + kg*16 + quad*4 + rg][q = qw + l16]
      const int q = qw + l16;
      float sv[16];
      if (k0 + 63 <= qw) {  // wave-uniform full tile: no mask needed
#pragma unroll
        for (int kg = 0; kg < 4; kg++)
#pragma unroll
          for (int rg = 0; rg < 4; rg++) sv[kg * 4 + rg] = s[kg][rg] * SCALE2;
      } else {
#pragma unroll
        for (int kg = 0; kg < 4; kg++)
#pragma unroll
          for (int rg = 0; rg < 4; rg++) {
            int key = k0 + kg * 16 + quad * 4 + rg;
            sv[kg * 4 + rg] = (key > q) ? -1e30f : s[kg][rg] * SCALE2;
          }
      }
      float mx = sv[0];
#pragma unroll
      for (int j = 1; j < 16; j++) mx = fmaxf(mx, sv[j]);
      mx = fmaxf(mx, __shfl_xor(mx, 16));
      mx = fmaxf(mx, __shfl_xor(mx, 32));
      if (__any(mx > mL)) {  // new max somewhere in wave: rescale path
        float mn = fmaxf(mL, mx);
        float alpha = exp2f(mL - mn);
        mL = mn;
        float al[4];
#pragma unroll
        for (int rg = 0; rg < 4; rg++) al[rg] = __shfl(alpha, (ln & 48) | (quad * 4 + rg));
#pragma unroll
        for (int f = 0; f < 9; f++)
#pragma unroll
          for (int rg = 0; rg < 4; rg++) o[f][rg] *= al[rg];
      }
      float p[16];
#pragma unroll
      for (int j = 0; j < 16; j++) p[j] = exp2f(sv[j] - mL);
#pragma unroll
      for (int kg = 0; kg < 4; kg++) {
        uint2 t2;
        t2.x = pk2(p[kg * 4 + 0], p[kg * 4 + 1]);
        t2.y = pk2(p[kg * 4 + 2], p[kg * 4 + 3]);
        *(uint2*)&Ps[w][l16 * PS_S + kg * 16 + quad * 4] = t2;
      }
      __asm__ volatile("s_waitcnt lgkmcnt(0)" ::: "memory");  // per-wave Ps write->read
      // PV: A = P (m=q=l16, k=key), B = V^T rows (f=8 -> ones rows = row sums)
      s16x8 pa0 = *(const s16x8*)&Ps[w][l16 * PS_S + quad * 8];
      s16x8 pa1 = *(const s16x8*)&Ps[w][l16 * PS_S + 32 + quad * 8];
#pragma unroll
      for (int f = 0; f < 9; f++) {
        s16x8 vb0 = *(const s16x8*)&Vt[(f * 16 + l16) * VT_S + quad * 8];
        o[f] = __builtin_amdgcn_mfma_f32_16x16x32_bf16(pa0, vb0, o[f], 0, 0, 0);
        s16x8 vb1 = *(const s16x8*)&Vt[(f * 16 + l16) * VT_S + 32 + quad * 8];
        o[f] = __builtin_amdgcn_mfma_f32_16x16x32_bf16(pa1, vb1, o[f], 0, 0, 0);
      }
    }

    float inv[4];
#pragma unroll
    for (int rg = 0; rg < 4; rg++) inv[rg] = 1.0f / o[8][rg];  // row-sum from ones rows
#pragma unroll
    for (int f = 0; f < 8; f++) {
#pragma unroll
      for (int rg = 0; rg < 4; rg++) {
        int qq = qw + quad * 4 + rg;
        O[(size_t)(b * T_ + qq) * DM + h * HD_ + f * 16 + l16] = f2b(o[f][rg] * inv[rg]);
      }
    }
  }
}

// ---------------- launch ----------------
extern "C" void kernel_launch(void* const* d_in, const int* in_sizes, int n_in,
                              void* d_out, int out_size, void* d_ws, size_t ws_size,
                              hipStream_t stream) {
  const float* x    = (const float*)d_in[0];
  const float* fr   = (const float*)d_in[1];
  const float* wdkv = (const float*)d_in[2];
  const float* wuk  = (const float*)d_in[3];
  const float* wuv  = (const float*)d_in[4];
  const float* wkr  = (const float*)d_in[5];
  const float* wdq  = (const float*)d_in[6];
  const float* wuq  = (const float*)d_in[7];
  const float* wqr  = (const float*)d_in[8];
  const float* wo   = (const float*)d_in[9];
  u16* ws = (u16*)d_ws;

  const int M1 = 1048576;
  u16* x_bf  = ws;                 // 8M (dead after gx) -> Om overlays
  u16* Om    = ws;                 // 8M [flash..g8]
  u16* Kc    = ws + 8 * M1;        // 8M (b,t,h*hd)
  u16* VTm   = ws + 16 * M1;       // 8M (b,h*hd,t)
  u16* Qc    = ws + 24 * M1;       // 8M (b,t,h*hd)
  u16* Qr    = ws + 32 * M1;       // 4M (b,t,h,r) RAW (rope fused in flash)
  u16* W     = ws + 36 * M1;       // 4M transpose arena (serial reuse)
  u16* cKV   = ws + 40 * M1;       // 2M
  u16* cQ    = ws + 42 * M1;       // 4M
  u16* fr_bf = ws + 46 * M1;       // 65536
  u16* kr_bf = fr_bf + 65536;      // 262144

  float* out_y   = (float*)d_out;              // (b,t,2048)
  float* out_ckv = (float*)d_out + 8388608;    // (b,t,512)
  float* out_kr  = (float*)d_out + 10485760;   // (b,t,64)
  (void)in_sizes; (void)n_in; (void)out_size; (void)ws_size;

  dim3 blk(256);

  // TA: conv x, conv fr, transpose gx weights
  ta_k<<<dim3(9056), blk, 0, stream>>>(x, fr, x_bf, fr_bf, wdkv, wkr, wdq, W);
  // gx: [cKV | K_r(rope) | cQ] = x @ [W_DKV | W_KR | W_DQ]
  gemm_bf16<6><<<dim3(13, 32), blk, 0, stream>>>(x_bf, W, cKV, kr_bf, cQ, out_ckv, out_kr, fr_bf,
                                                 4096, 1600, 2048);
  // gkv: [K_c | V^T] = c_KV @ [W_UK | W_UV]
  tb1_k<<<dim3(512), blk, 0, stream>>>(wuk, wuv, W);
  gemm_bf16<4><<<dim3(32, 32), blk, 0, stream>>>(cKV, W, Kc, VTm, nullptr, nullptr, nullptr, nullptr,
                                                 4096, 4096, 512);
  // gq: [Q_c | Q_r-raw] = c_Q @ [W_UQ | W_QR]
  tb2_k<<<dim3(768), blk, 0, stream>>>(wuq, wqr, W);
  gemm_bf16<5><<<dim3(24, 32), blk, 0, stream>>>(cQ, W, Qc, Qr, nullptr, nullptr, nullptr, nullptr,
                                                 4096, 3072, 1024);
  // attention (Om overlays dead x_bf)
  flash_attn<<<dim3(32, 16), blk, 0, stream>>>(Qc, Qr, Kc, kr_bf, VTm, fr_bf, Om);
  // y = attn_out @ W_O
  tc_k<<<dim3(1024), blk, 0, stream>>>(wo, W);
  gemm_bf16<2><<<dim3(16, 32), blk, 0, stream>>>(Om, W, nullptr, nullptr, nullptr, out_y, nullptr,
                                                 nullptr, 4096, 2048, 2048);
}